// Round 1
// 1742.643 us; speedup vs baseline: 1.4591x; 1.4591x over previous
//
#include <hip/hip_runtime.h>
#include <stdint.h>

#define SLEN    512
#define IDIM    256
#define HDIM    512
#define NROW    256          // 2 sequences x 128 batch rows
#define KP      776          // Ab LDS row stride in halfs (768 + 8)
#define NSTEP   512
#define NGRP    16           // batch groups (16 rows each)
#define GWG     16           // WGs (column groups) per batch group

typedef __attribute__((ext_vector_type(8))) _Float16 half8;
typedef __attribute__((ext_vector_type(4))) float   f32x4;
typedef __attribute__((ext_vector_type(4))) int     i32x4;

__device__ __forceinline__ float sigm(float x)   { return 1.0f / (1.0f + __expf(-x)); }
__device__ __forceinline__ float tanh_f(float x) { return 2.0f / (1.0f + __expf(-2.0f * x)) - 1.0f; }

__device__ __forceinline__ half8 cvt8(float4 a, float4 b) {
    half8 v;
    v[0] = (_Float16)a.x; v[1] = (_Float16)a.y; v[2] = (_Float16)a.z; v[3] = (_Float16)a.w;
    v[4] = (_Float16)b.x; v[5] = (_Float16)b.y; v[6] = (_Float16)b.z; v[7] = (_Float16)b.w;
    return v;
}

union hu { _Float16 h; unsigned short u; };

// Persistent LSTM. 256 WGs = 16 batch groups (16 rows) x 16 column groups (32 H-cols).
// Round-1 changes vs previous best:
//  - per-WAVE flags (64/group) posted right after each wave's own vmcnt(0) drain:
//    removes the group __syncthreads AND the 16-deep atomic-RMW serialization from
//    the producer->consumer signal path. Consumer polls all 64 flags with one
//    coalesced 64-lane load + __all.
//  - adjacent-column M-tile remap (cc1 = cc0+1): h store is one packed dword/lane
//    (was 2 scattered shorts); h load is 4x dwordx4 sc0 sc1 (was 8x 8B atomics).
//  - GEMM split: x-part (kk 0..7) + x prefetch issue run BEFORE the flag wait;
//    x staging runs between cell update and the h store. Only the h-dependent
//    work remains on the serial chain. Still 2 barriers/step.
__global__ __launch_bounds__(256, 1)
void lstm_persistent(const float* __restrict__ x0, const float* __restrict__ x1,
                     const float* __restrict__ wih, const float* __restrict__ whh,
                     const float* __restrict__ bih, const float* __restrict__ bhh,
                     _Float16* __restrict__ hb, int* __restrict__ flg,
                     float* __restrict__ out) {
    __shared__ __align__(16) _Float16 Ab[16 * KP];

    const int tid  = threadIdx.x;
    const int lane = tid & 63;
    const int w    = tid >> 6;       // wave 0..3
    const int quad = lane >> 4;
    const int l16  = lane & 15;
    const int igrp = blockIdx.x & 15;    // batch group (16 rows)
    const int jcg  = blockIdx.x >> 4;    // column group (32 H-cols)

    // ---- W A-frags: global fp32 -> f16 regs/AGPRs, once ----
    // tile row m: gate q=m&3, col-in-tile ccl=m>>2.
    // NEW adjacent-col map: tile0 col = jcg*32 + w*8 + ccl*2, tile1 col = +1.
    const int q0  = l16 & 3, ccl = l16 >> 2;
    const int colb = jcg * 32 + w * 8 + ccl * 2;
    const int gc0 = q0 * HDIM + colb;
    const int gc1 = gc0 + 1;
    half8 wf0[24], wf1[24];
#pragma unroll
    for (int kk = 0; kk < 24; ++kk) {
        int k0 = kk * 32 + quad * 8;
        const float* sA = (k0 < IDIM) ? wih + (size_t)gc0 * IDIM + k0
                                      : whh + (size_t)gc0 * HDIM + (k0 - IDIM);
        const float* sB = (k0 < IDIM) ? wih + (size_t)gc1 * IDIM + k0
                                      : whh + (size_t)gc1 * HDIM + (k0 - IDIM);
        wf0[kk] = cvt8(*(const float4*)sA, *(const float4*)(sA + 4));
        wf1[kk] = cvt8(*(const float4*)sB, *(const float4*)(sB + 4));
    }

    // ---- bias: C-frag reg q = gate q at col (quad*2 + tile) ----
    float bias0[4], bias1[4];
#pragma unroll
    for (int q = 0; q < 4; ++q) {
        int g0 = q * HDIM + jcg * 32 + w * 8 + quad * 2;
        bias0[q] = bih[g0] + bhh[g0];
        bias1[q] = bih[g0 + 1] + bhh[g0 + 1];
    }

    const float* xp  = (igrp < 8) ? x0 : x1;
    const int   brow = (igrp & 7) * 16;
    const int   r0   = tid >> 5;            // my x rows r0, r0+8
    const int   o0   = (tid & 31) * 8;      // my x col chunk
    const int   grow = igrp * 16 + l16;     // my batch row (global)
    const int   cc0  = jcg * 32 + w * 8 + quad * 2;  // my H-cols (cc0, cc0+1)

    const int* fpoll = flg + igrp * 64 + lane;          // 64 wave-flags of my group
    int*       fmine = flg + igrp * 64 + jcg * 4 + w;   // my wave's flag

    float c0 = 0.f, c1 = 0.f;
    int gaveup = 0;   // spin-timeout failsafe

    // ---- prologue: prefetch + stage x(0) ----
    {
        const float* xr0 = xp + ((size_t)(brow + r0) * SLEN + 0) * IDIM + o0;
        const float* xr1 = xr0 + (size_t)8 * SLEN * IDIM;
        float4 pa = *(const float4*)xr0, pb = *(const float4*)(xr0 + 4);
        float4 pc = *(const float4*)xr1, pd = *(const float4*)(xr1 + 4);
        *(half8*)&Ab[r0 * KP + o0]       = cvt8(pa, pb);
        *(half8*)&Ab[(r0 + 8) * KP + o0] = cvt8(pc, pd);
    }

#pragma unroll 1
    for (int t = 0; t < NSTEP; ++t) {
        __syncthreads();   // A1: x(t) staged; all waves done with Ab from step t-1

        f32x4 acc0 = {bias0[0], bias0[1], bias0[2], bias0[3]};
        f32x4 acc1 = {bias1[0], bias1[1], bias1[2], bias1[3]};

        // ---- issue x(t+1) prefetch early (consumed at end of this iter) ----
        float4 pa, pb, pc, pd;
        if (t < NSTEP - 1) {
            const float* xr0 = xp + ((size_t)(brow + r0) * SLEN + (t + 1)) * IDIM + o0;
            const float* xr1 = xr0 + (size_t)8 * SLEN * IDIM;
            pa = *(const float4*)xr0; pb = *(const float4*)(xr0 + 4);
            pc = *(const float4*)xr1; pd = *(const float4*)(xr1 + 4);
        }

        // ---- x-part GEMM (K=256, kk 0..7): independent of h_{t-1} ----
        const _Float16* ab = &Ab[l16 * KP + quad * 8];
#pragma unroll
        for (int kk = 0; kk < 8; ++kk) {
            half8 bf = *(const half8*)(ab + kk * 32);
            acc0 = __builtin_amdgcn_mfma_f32_16x16x32_f16(wf0[kk], bf, acc0, 0, 0, 0);
            acc1 = __builtin_amdgcn_mfma_f32_16x16x32_f16(wf1[kk], bf, acc1, 0, 0, 0);
        }

        // ---- wait: all 64 producer waves of this group signalled step t-1 ----
        if (t > 0 && !gaveup) {
            int it = 0;
            while (true) {
                int f;
                asm volatile("global_load_dword %0, %1, off sc0 sc1\n\t"
                             "s_waitcnt vmcnt(0)"
                             : "=v"(f) : "v"(fpoll) : "memory");
                if (__all(f >= t)) break;
                __builtin_amdgcn_s_sleep(1);
                if (++it > (1 << 20)) { gaveup = 1; break; }
            }
            __builtin_amdgcn_fence(__ATOMIC_ACQUIRE, "workgroup");
        }

        // ---- load h_{t-1} (16 KB) as 4x dwordx4 sc0 sc1, stage into LDS ----
        {
            const char* hs = (const char*)
                (hb + (size_t)((t + 1) & 1) * (NROW * HDIM) + (size_t)(igrp * 16) * HDIM);
            i32x4 v0_, v1_, v2_, v3_;
            asm volatile(
                "global_load_dwordx4 %0, %4, off sc0 sc1\n\t"
                "global_load_dwordx4 %1, %5, off sc0 sc1\n\t"
                "global_load_dwordx4 %2, %6, off sc0 sc1\n\t"
                "global_load_dwordx4 %3, %7, off sc0 sc1\n\t"
                "s_waitcnt vmcnt(0)"
                : "=&v"(v0_), "=&v"(v1_), "=&v"(v2_), "=&v"(v3_)
                : "v"(hs + (size_t)(tid      ) * 16), "v"(hs + (size_t)(tid + 256) * 16),
                  "v"(hs + (size_t)(tid + 512) * 16), "v"(hs + (size_t)(tid + 768) * 16)
                : "memory");
            *(i32x4*)&Ab[((tid      ) >> 6) * KP + IDIM + ((tid      ) & 63) * 8] = v0_;
            *(i32x4*)&Ab[((tid + 256) >> 6) * KP + IDIM + ((tid + 256) & 63) * 8] = v1_;
            *(i32x4*)&Ab[((tid + 512) >> 6) * KP + IDIM + ((tid + 512) & 63) * 8] = v2_;
            *(i32x4*)&Ab[((tid + 768) >> 6) * KP + IDIM + ((tid + 768) & 63) * 8] = v3_;
        }
        __syncthreads();   // A2: h staged

        // ---- h-part GEMM (K=512, kk 8..23) ----
#pragma unroll
        for (int kk = 8; kk < 24; ++kk) {
            half8 bf = *(const half8*)(ab + kk * 32);
            acc0 = __builtin_amdgcn_mfma_f32_16x16x32_f16(wf0[kk], bf, acc0, 0, 0, 0);
            acc1 = __builtin_amdgcn_mfma_f32_16x16x32_f16(wf1[kk], bf, acc1, 0, 0, 0);
        }

        // ---- cell update (regs 0..3 = i,f,g,o), fp32 ----
        float i0 = sigm(acc0[0]), f0 = sigm(acc0[1]), g0 = tanh_f(acc0[2]), o0g = sigm(acc0[3]);
        c0 = f0 * c0 + i0 * g0;
        float h0 = o0g * tanh_f(c0);
        float i1 = sigm(acc1[0]), f1 = sigm(acc1[1]), g1 = tanh_f(acc1[2]), o1g = sigm(acc1[3]);
        c1 = f1 * c1 + i1 * g1;
        float h1 = o1g * tanh_f(c1);

        if (t < NSTEP - 1) {
            // stage x(t+1) first (consumes prefetch regs -> they retire before drain)
            *(half8*)&Ab[r0 * KP + o0]       = cvt8(pa, pb);
            *(half8*)&Ab[(r0 + 8) * KP + o0] = cvt8(pc, pd);

            // packed dword h store -> LLC; per-wave drain; wave-lane0 posts flag.
            _Float16* hd = hb + (size_t)(t & 1) * (NROW * HDIM) + (size_t)grow * HDIM;
            hu u0; u0.h = (_Float16)h0;
            hu u1; u1.h = (_Float16)h1;
            unsigned int hp = (unsigned int)u0.u | ((unsigned int)u1.u << 16);
            asm volatile(
                "global_store_dword %0, %1, off sc0 sc1\n\t"
                "s_waitcnt vmcnt(0)"
                :: "v"((int*)(hd + cc0)), "v"(hp)
                : "memory");
            if (lane == 0) {
                int fv = t + 1;
                asm volatile("global_store_dword %0, %1, off sc0 sc1"
                             :: "v"(fmine), "v"(fv) : "memory");
            }
        } else {
            float2 ov; ov.x = h0; ov.y = h1;
            *(float2*)(out + (size_t)grow * HDIM + cc0) = ov;
        }
    }
}

extern "C" void kernel_launch(void* const* d_in, const int* in_sizes, int n_in,
                              void* d_out, int out_size, void* d_ws, size_t ws_size,
                              hipStream_t stream) {
    const float* x0  = (const float*)d_in[0];   // [128,512,256] fp32
    const float* x1  = (const float*)d_in[1];
    const float* wih = (const float*)d_in[2];   // [2048,256]
    const float* whh = (const float*)d_in[3];   // [2048,512]
    const float* bih = (const float*)d_in[4];   // [2048]
    const float* bhh = (const float*)d_in[5];   // [2048]

    // ws: h ping-pong (2 x 256 KB f16) + per-(group,wave) flags (16 x 64 ints)
    _Float16* hb = (_Float16*)d_ws;
    int* flg = (int*)((char*)d_ws + (size_t)2 * NROW * HDIM * sizeof(_Float16));
    size_t zbytes = (size_t)2 * NROW * HDIM * sizeof(_Float16)
                  + (size_t)NGRP * 64 * sizeof(int);
    hipMemsetAsync(d_ws, 0, zbytes, stream);   // zero h_{-1} + flags (ws is 0xAA-poisoned)

    lstm_persistent<<<dim3(256), dim3(256), 0, stream>>>(
        x0, x1, wih, whh, bih, bhh, hb, flg, (float*)d_out);
}